// Round 19
// baseline (1112.926 us; speedup 1.0000x reference)
//
#include <hip/hip_runtime.h>
#include <hip/hip_bf16.h>

using bf16x8 = __attribute__((ext_vector_type(8))) short;
using f32x4  = __attribute__((ext_vector_type(4))) float;
using u16x4  = __attribute__((ext_vector_type(4))) unsigned short;

#define DEVI static __device__ __forceinline__
#define SBAR() asm volatile("s_barrier" ::: "memory")

DEVI unsigned short f2b(float f) {           // f32 -> bf16 RNE
  unsigned int u = __float_as_uint(f);
  u += 0x7FFFu + ((u >> 16) & 1u);
  return (unsigned short)(u >> 16);
}

DEVI void gload16(const unsigned short* g, unsigned short* l) {
  __builtin_amdgcn_global_load_lds(
      (const __attribute__((address_space(1))) unsigned int*)g,
      (__attribute__((address_space(3))) unsigned int*)l, 16, 0, 0);
}

DEVI float wred_max16(float v) {
#pragma unroll
  for (int m = 1; m < 16; m <<= 1) v = fmaxf(v, __shfl_xor(v, m, 64));
  return v;
}
DEVI float wred_sum16(float v) {
#pragma unroll
  for (int m = 1; m < 16; m <<= 1) v += __shfl_xor(v, m, 64);
  return v;
}

// ---------------- elementwise / pack kernels ----------------

__global__ void cvt_kernel(const float* __restrict__ in,
                           unsigned short* __restrict__ out, int n4) {
  int i = blockIdx.x * blockDim.x + threadIdx.x;
  const int stride = gridDim.x * blockDim.x;
  for (; i < n4; i += stride) {
    const float4 v = ((const float4*)in)[i];
    u16x4 o;
    o[0] = f2b(v.x); o[1] = f2b(v.y); o[2] = f2b(v.z); o[3] = f2b(v.w);
    ((u16x4*)out)[i] = o;
  }
}

__global__ void pack_w(const float* __restrict__ s0,
                       const float* __restrict__ s1,
                       const float* __restrict__ s2,
                       int sub, unsigned short* __restrict__ dst, int nm) {
  const int r = blockIdx.x;
  const int m = blockIdx.y;
  const int l = blockIdx.z;
  const float* src = (m == 0 ? s0 : m == 1 ? s1 : s2)
                   + (size_t)(l * 2 + sub) * 1048576 + (size_t)r * 1024;
  unsigned short* d = dst + ((size_t)(l * nm + m) * 1024 + r) * 1024;
  const int col = threadIdx.x * 4;
  const float4 v = *(const float4*)(src + col);
  u16x4 o;
  o[0] = f2b(v.x); o[1] = f2b(v.y); o[2] = f2b(v.z); o[3] = f2b(v.w);
  *(u16x4*)(d + col) = o;
}

__global__ void pack_bias(const float* __restrict__ s0,
                          const float* __restrict__ s1,
                          const float* __restrict__ s2,
                          int sub, float* __restrict__ dst, int nm) {
  const int m = blockIdx.x, l = blockIdx.y;
  const float* src = (m == 0 ? s0 : m == 1 ? s1 : s2) + (size_t)(l * 2 + sub) * 1024;
  float* d = dst + ((size_t)l * nm + m) * 1024;
  const int i = threadIdx.x * 4;
  *(float4*)(d + i) = *(const float4*)(src + i);
}

__global__ void embed_kernel(const int* __restrict__ ids,
                             const float* __restrict__ emb,
                             const float* __restrict__ pe,
                             float* __restrict__ x) {
  const int row = blockIdx.x;
  const int t = row & 511;
  const int col = threadIdx.x * 4;
  const int id = ids[row];
  const float4 e = *(const float4*)(emb + (size_t)id * 1024 + col);
  const float4 p = *(const float4*)(pe + (size_t)t * 1024 + col);
  float4 o;
  o.x = e.x * 32.f + p.x; o.y = e.y * 32.f + p.y;
  o.z = e.z * 32.f + p.z; o.w = e.w * 32.f + p.w;
  *(float4*)(x + (size_t)row * 1024 + col) = o;
}

__global__ void ln_kernel(const float* __restrict__ x,
                          const float* __restrict__ g,
                          const float* __restrict__ b,
                          unsigned short* __restrict__ out) {
  const int row = blockIdx.x;
  const int l = threadIdx.x;
  const float4* xr = (const float4*)(x + (size_t)row * 1024);
  float4 v[4];
  float s = 0.f;
#pragma unroll
  for (int i = 0; i < 4; ++i) {
    v[i] = xr[l * 4 + i];
    s += v[i].x + v[i].y + v[i].z + v[i].w;
  }
#pragma unroll
  for (int m = 1; m < 64; m <<= 1) s += __shfl_xor(s, m, 64);
  const float mean = s * (1.f / 1024.f);
  float vs = 0.f;
#pragma unroll
  for (int i = 0; i < 4; ++i) {
    float dx = v[i].x - mean, dy = v[i].y - mean, dz = v[i].z - mean, dw = v[i].w - mean;
    vs += dx * dx + dy * dy + dz * dz + dw * dw;
  }
#pragma unroll
  for (int m = 1; m < 64; m <<= 1) vs += __shfl_xor(vs, m, 64);
  const float inv = rsqrtf(vs * (1.f / 1024.f) + 1e-5f);
#pragma unroll
  for (int i = 0; i < 4; ++i) {
    const int col = l * 16 + i * 4;
    const float4 gg = *(const float4*)(g + col);
    const float4 bb = *(const float4*)(b + col);
    u16x4 o;
    o[0] = f2b((v[i].x - mean) * inv * gg.x + bb.x);
    o[1] = f2b((v[i].y - mean) * inv * gg.y + bb.y);
    o[2] = f2b((v[i].z - mean) * inv * gg.z + bb.z);
    o[3] = f2b((v[i].w - mean) * inv * gg.w + bb.w);
    *(u16x4*)(out + (size_t)row * 1024 + col) = o;
  }
}

// Fused FFN2 reduce + next LayerNorm (layers 0,1):
// x = c + p0+p1+p2+p3 + bias;  hb = bf16(LN(x)*g + e)
__global__ void reduce4_ln_kernel(const float* __restrict__ c,
                                  const float* __restrict__ pbuf,
                                  const float* __restrict__ bias,
                                  const float* __restrict__ g,
                                  const float* __restrict__ e,
                                  float* __restrict__ x,
                                  unsigned short* __restrict__ hb) {
  const int row = blockIdx.x;
  const int l = threadIdx.x;            // 64 lanes, 16 elems each
  const size_t base = (size_t)row * 1024;
  const float4* cc = (const float4*)(c + base);
  const float4* p0 = (const float4*)(pbuf + base);
  const float4* p1 = (const float4*)(pbuf + 4194304 + base);
  const float4* p2 = (const float4*)(pbuf + 2 * 4194304 + base);
  const float4* p3 = (const float4*)(pbuf + 3 * 4194304 + base);
  float4 v[4];
  float s = 0.f;
#pragma unroll
  for (int i = 0; i < 4; ++i) {
    const int fi = l * 4 + i;
    const float4 a = cc[fi];
    const float4 b0 = p0[fi], b1 = p1[fi], b2v = p2[fi], b3 = p3[fi];
    const float4 bb = ((const float4*)bias)[fi & 255];
    float4 o;
    o.x = a.x + (b0.x + b1.x) + (b2v.x + b3.x) + bb.x;
    o.y = a.y + (b0.y + b1.y) + (b2v.y + b3.y) + bb.y;
    o.z = a.z + (b0.z + b1.z) + (b2v.z + b3.z) + bb.z;
    o.w = a.w + (b0.w + b1.w) + (b2v.w + b3.w) + bb.w;
    v[i] = o;
    s += o.x + o.y + o.z + o.w;
    *(float4*)(x + base + fi * 4) = o;
  }
#pragma unroll
  for (int m = 1; m < 64; m <<= 1) s += __shfl_xor(s, m, 64);
  const float mean = s * (1.f / 1024.f);
  float vs = 0.f;
#pragma unroll
  for (int i = 0; i < 4; ++i) {
    float dx = v[i].x - mean, dy = v[i].y - mean, dz = v[i].z - mean, dw = v[i].w - mean;
    vs += dx * dx + dy * dy + dz * dz + dw * dw;
  }
#pragma unroll
  for (int m = 1; m < 64; m <<= 1) vs += __shfl_xor(vs, m, 64);
  const float inv = rsqrtf(vs * (1.f / 1024.f) + 1e-5f);
#pragma unroll
  for (int i = 0; i < 4; ++i) {
    const int col = l * 16 + i * 4;
    const float4 gg = *(const float4*)(g + col);
    const float4 bb = *(const float4*)(e + col);
    u16x4 o;
    o[0] = f2b((v[i].x - mean) * inv * gg.x + bb.x);
    o[1] = f2b((v[i].y - mean) * inv * gg.y + bb.y);
    o[2] = f2b((v[i].z - mean) * inv * gg.z + bb.z);
    o[3] = f2b((v[i].w - mean) * inv * gg.w + bb.w);
    *(u16x4*)(hb + base + col) = o;
  }
}

// ------------- 8-phase fat GEMM core: 256x256 tile, 8 waves (m201 port) -------------

template<int LDA, int LDB>
DEVI void gemm8p_core(const unsigned short* __restrict__ A,
                      const unsigned short* __restrict__ Bw,
                      int m0, int n0, int kofs,
                      unsigned short* AsE, unsigned short* BsE,
                      unsigned short* AsO, unsigned short* BsO,
                      int tid, f32x4 (&acc)[8][4]) {
  constexpr int NT = 16;
  const int lane = tid & 63;
  const int wave = tid >> 6;
  const int wr = wave >> 2;
  const int wc = wave & 3;
  const int ro = lane & 15;
  const int hi = lane >> 4;

  auto stA = [&](unsigned short* buf, int q, int kt) {
    const int row = tid >> 3;
    const int lc = (tid & 7) ^ (row & 7);
    gload16(A + (size_t)(m0 + q * 64 + row) * LDA + kofs + kt * 64 + lc * 8,
            buf + q * 4096 + tid * 8);
  };
  auto stB = [&](unsigned short* buf, int q, int kt) {
    const int row = tid >> 3;
    const int lc = (tid & 7) ^ (row & 7);
    gload16(Bw + (size_t)(n0 + q * 64 + row) * LDB + kofs + kt * 64 + lc * 8,
            buf + q * 4096 + tid * 8);
  };

  bf16x8 af[4][2], bfL[2][2], bfR[2][2];
  auto ldAL = [&](const unsigned short* buf) {
#pragma unroll
    for (int mi = 0; mi < 4; ++mi) {
      const int r = wr * 128 + mi * 16 + ro;
#pragma unroll
      for (int ks = 0; ks < 2; ++ks)
        af[mi][ks] = *(const bf16x8*)&buf[r * 64 + (((ks << 2) + hi) ^ (r & 7)) * 8];
    }
  };
  auto ldAH = [&](const unsigned short* buf) {
#pragma unroll
    for (int mi = 0; mi < 4; ++mi) {
      const int r = wr * 128 + 64 + mi * 16 + ro;
#pragma unroll
      for (int ks = 0; ks < 2; ++ks)
        af[mi][ks] = *(const bf16x8*)&buf[r * 64 + (((ks << 2) + hi) ^ (r & 7)) * 8];
    }
  };
  auto ldBL = [&](const unsigned short* buf) {
#pragma unroll
    for (int nj = 0; nj < 2; ++nj) {
      const int r = wc * 64 + nj * 16 + ro;
#pragma unroll
      for (int ks = 0; ks < 2; ++ks)
        bfL[nj][ks] = *(const bf16x8*)&buf[r * 64 + (((ks << 2) + hi) ^ (r & 7)) * 8];
    }
  };
  auto ldBR = [&](const unsigned short* buf) {
#pragma unroll
    for (int nj = 0; nj < 2; ++nj) {
      const int r = wc * 64 + 32 + nj * 16 + ro;
#pragma unroll
      for (int ks = 0; ks < 2; ++ks)
        bfR[nj][ks] = *(const bf16x8*)&buf[r * 64 + (((ks << 2) + hi) ^ (r & 7)) * 8];
    }
  };
  auto mmQ = [&](bf16x8 (&bf)[2][2], int mo, int no) {
    __builtin_amdgcn_s_setprio(1);
#pragma unroll
    for (int ks = 0; ks < 2; ++ks)
#pragma unroll
      for (int mi = 0; mi < 4; ++mi)
#pragma unroll
        for (int nj = 0; nj < 2; ++nj)
          acc[mo + mi][no + nj] =
              __builtin_amdgcn_mfma_f32_16x16x32_bf16(af[mi][ks], bf[nj][ks],
                                                      acc[mo + mi][no + nj], 0, 0, 0);
    __builtin_amdgcn_s_setprio(0);
  };

  stA(AsE, 0, 0); stA(AsE, 1, 0); stA(AsE, 2, 0); stA(AsE, 3, 0);
  stB(BsE, 0, 0); stB(BsE, 1, 0); stB(BsE, 2, 0); stB(BsE, 3, 0);
  stA(AsO, 0, 1); stA(AsO, 1, 1); stA(AsO, 2, 1); stA(AsO, 3, 1);
  stB(BsO, 0, 1); stB(BsO, 1, 1);
  asm volatile("s_waitcnt vmcnt(0)" ::: "memory");
  SBAR();

  for (int t = 0; t < NT; t += 2) {
    const bool last = (t + 2 >= NT);
    ldAL(AsE); ldBL(BsE);
    stB(BsO, 2, t + 1); stB(BsO, 3, t + 1);
    SBAR(); mmQ(bfL, 0, 0); SBAR();
    ldBR(BsE);
    if (!last) { stA(AsE, 0, t + 2); stA(AsE, 2, t + 2); }
    SBAR(); mmQ(bfR, 0, 2); SBAR();
    ldAH(AsE);
    if (!last) { stB(BsE, 0, t + 2); stB(BsE, 1, t + 2); }
    SBAR(); mmQ(bfL, 4, 0); SBAR();
    if (!last) {
      stA(AsE, 1, t + 2); stA(AsE, 3, t + 2);
      asm volatile("s_waitcnt vmcnt(6)" ::: "memory");
    } else {
      asm volatile("s_waitcnt vmcnt(0)" ::: "memory");
    }
    SBAR(); mmQ(bfR, 4, 2); SBAR();
    ldAL(AsO); ldBL(BsO);
    if (!last) { stB(BsE, 2, t + 2); stB(BsE, 3, t + 2); }
    SBAR(); mmQ(bfL, 0, 0); SBAR();
    ldBR(BsO);
    if (!last) { stA(AsO, 0, t + 3); stA(AsO, 2, t + 3); }
    SBAR(); mmQ(bfR, 0, 2); SBAR();
    ldAH(AsO);
    if (!last) { stB(BsO, 0, t + 3); stB(BsO, 1, t + 3); }
    SBAR(); mmQ(bfL, 4, 0); SBAR();
    if (!last) {
      stA(AsO, 1, t + 3); stA(AsO, 3, t + 3);
      asm volatile("s_waitcnt vmcnt(6)" ::: "memory");
    }
    SBAR(); mmQ(bfR, 4, 2); SBAR();
  }
}

// VT = 0: plain.  VT = 1: self-QKV (N=3072) — cols >=2048 are V, written ONLY
// transposed into vt[b][h][64][512].  VT = 2: merged KV (N=6144) — cols with
// (cg & 2047) >= 1024 are layer cg>>11's V, written only transposed into
// vt + layer*4194304. V-tile boundaries are 256-aligned -> block-uniform.
template<int EPI, int VT>
__global__ __launch_bounds__(512, 1) void gemm8p(
    const unsigned short* __restrict__ A,
    const unsigned short* __restrict__ Bw,
    const float* __restrict__ bias,
    int N, unsigned short* __restrict__ out0,
    unsigned short* __restrict__ vt) {
  __shared__ alignas(16) unsigned short AsE[256 * 64];
  __shared__ alignas(16) unsigned short BsE[256 * 64];
  __shared__ alignas(16) unsigned short AsO[256 * 64];
  __shared__ alignas(16) unsigned short BsO[256 * 64];
  const int tid = threadIdx.x;
  int id = blockIdx.x;
  const int nwg = gridDim.x;
  id = (id & 7) * (nwg >> 3) + (id >> 3);
  const int nn = N >> 8;
  const int bx = id % nn;
  const int by = id / nn;
  const int m0 = by * 256;
  const int n0 = bx * 256;

  f32x4 acc[8][4];
#pragma unroll
  for (int i = 0; i < 8; ++i)
#pragma unroll
    for (int j = 0; j < 4; ++j) acc[i][j] = f32x4{0.f, 0.f, 0.f, 0.f};

  gemm8p_core<1024, 1024>(A, Bw, m0, n0, 0, AsE, BsE, AsO, BsO, tid, acc);

  const int lane = tid & 63;
  const int wave = tid >> 6;
  const int wr = wave >> 2, wc = wave & 3;
  const int ro = lane & 15, hi = lane >> 4;
  const int r4 = hi * 4;
#pragma unroll
  for (int mi = 0; mi < 8; ++mi) {
#pragma unroll
    for (int nj = 0; nj < 4; ++nj) {
      const int cg = n0 + wc * 64 + nj * 16 + ro;
      const float bv = bias[cg];
      const int rg0 = m0 + wr * 128 + mi * 16 + r4;
      const bool isV1 = (VT == 1) && (cg >= 2048);
      const bool isV2 = (VT == 2) && ((cg & 2047) >= 1024);
      if (isV1 || isV2) {
        u16x4 o;
#pragma unroll
        for (int q = 0; q < 4; ++q) o[q] = f2b(acc[mi][nj][q] + bv);
        const int b = rg0 >> 9, t = rg0 & 511;
        size_t dst;
        if (isV1) {
          const int hh = (cg - 2048) >> 6, d = (cg - 2048) & 63;
          dst = (((size_t)(b * 16 + hh) * 64 + d) << 9) + t;
        } else {
          const int layer = cg >> 11;
          const int cm = (cg & 2047) - 1024;
          dst = (size_t)layer * 4194304 +
                (((size_t)(b * 16 + (cm >> 6)) * 64 + (cm & 63)) << 9) + t;
        }
        *(u16x4*)&vt[dst] = o;
      } else {
#pragma unroll
        for (int q = 0; q < 4; ++q) {
          const float v = acc[mi][nj][q] + bv;
          out0[(size_t)(rg0 + q) * N + cg] = f2b(EPI == 1 ? fmaxf(v, 0.f) : v);
        }
      }
    }
  }
}

// FFN2 split-K=4 on the 8-phase engine: writes f32 partials pbuf[s][4096][1024].
__global__ __launch_bounds__(512, 1) void gemm_sk8(
    const unsigned short* __restrict__ A,
    const unsigned short* __restrict__ Bw,
    float* __restrict__ pbuf) {
  __shared__ alignas(16) unsigned short AsE[256 * 64];
  __shared__ alignas(16) unsigned short BsE[256 * 64];
  __shared__ alignas(16) unsigned short AsO[256 * 64];
  __shared__ alignas(16) unsigned short BsO[256 * 64];
  const int tid = threadIdx.x;
  int id = blockIdx.x;
  const int nwg = gridDim.x;               // 256
  id = (id & 7) * (nwg >> 3) + (id >> 3);  // XCD swizzle
  const int s  = id >> 6;                  // split 0..3
  const int r6 = id & 63;
  const int bx = r6 & 3;                   // 4 col tiles (N=1024)
  const int by = r6 >> 2;                  // 16 row tiles
  const int m0 = by * 256;
  const int n0 = bx * 256;

  f32x4 acc[8][4];
#pragma unroll
  for (int i = 0; i < 8; ++i)
#pragma unroll
    for (int j = 0; j < 4; ++j) acc[i][j] = f32x4{0.f, 0.f, 0.f, 0.f};

  gemm8p_core<4096, 4096>(A, Bw, m0, n0, s * 1024, AsE, BsE, AsO, BsO, tid, acc);

  float* out = pbuf + (size_t)s * 4096 * 1024;
  const int lane = tid & 63;
  const int wave = tid >> 6;
  const int wr = wave >> 2, wc = wave & 3;
  const int ro = lane & 15, hi = lane >> 4;
  const int r4 = hi * 4;
#pragma unroll
  for (int mi = 0; mi < 8; ++mi)
#pragma unroll
    for (int nj = 0; nj < 4; ++nj) {
      const int cg = n0 + wc * 64 + nj * 16 + ro;
#pragma unroll
      for (int q = 0; q < 4; ++q) {
        const int rg = m0 + wr * 128 + mi * 16 + r4 + q;
        out[(size_t)rg * 1024 + cg] = acc[mi][nj][q];
      }
    }
}

// xout = c + p0 + p1 + p2 + p3 + bias   (f32, vectorized; used for l=2)
__global__ void reduce4_kernel(const float* __restrict__ c,
                               const float* __restrict__ pbuf,
                               const float* __restrict__ bias,
                               float* __restrict__ xout) {
  const int n4 = 4096 * 1024 / 4;
  int i = blockIdx.x * blockDim.x + threadIdx.x;
  const int stride = gridDim.x * blockDim.x;
  const float4* p0 = (const float4*)pbuf;
  const float4* p1 = (const float4*)(pbuf + 4194304);
  const float4* p2 = (const float4*)(pbuf + 2 * 4194304);
  const float4* p3 = (const float4*)(pbuf + 3 * 4194304);
  for (; i < n4; i += stride) {
    const float4 cc = ((const float4*)c)[i];
    const float4 a0 = p0[i];
    const float4 a1 = p1[i];
    const float4 a2 = p2[i];
    const float4 a3 = p3[i];
    const float4 bb = ((const float4*)bias)[i & 255];
    float4 o;
    o.x = cc.x + (a0.x + a1.x) + (a2.x + a3.x) + bb.x;
    o.y = cc.y + (a0.y + a1.y) + (a2.y + a3.y) + bb.y;
    o.z = cc.z + (a0.z + a1.z) + (a2.z + a3.z) + bb.z;
    o.w = cc.w + (a0.w + a1.w) + (a2.w + a3.w) + bb.w;
    ((float4*)xout)[i] = o;
  }
}

// ------- skinny 4-phase GEMM: 128x128 tile, 4 waves, 16-MFMA phases -------
// Mini-port of the m201 schedule. Wave-tile 64x64 (wr=row-half, wc=col-half).
// Quarters = 32 rows (4 KB = 256 thr x 16B). A-low = {q0,q2} (read by mi 0,1
// of both wr), A-high = {q1,q3}; B fully read in its tile's first phase.
// Per 2-ktile iteration, 4 phases x {ds-read | 4 quarter-stages | bar |
// 16 MFMA setprio | bar}; counted vmcnt(4) at P2/P4. Region-safe:
//  P1 stages BO-q23,AO-q13(t+1)  [freed prev P3/P4; read P3/P4, cov. P2-wait]
//  P2 stages AE-q02,BE-q01(t+2)  [freed this P1; read next P1, cov. P4-wait]
//  P3 stages AE-q13,BE-q23(t+2)  [freed this P2/P1; read next P1/P2]
//  P4 stages AO-q02,BO-q01(t+3)  [freed this P3; read next P3]

enum { EPI_BF16 = 0, EPI_RELU_BF16 = 1, EPI_RES = 2, EPI_RES2 = 3 };

template<int EPI>
__global__ __launch_bounds__(256, 2) void gemm_s8(
    const unsigned short* __restrict__ A,
    const unsigned short* __restrict__ Bw,
    const float* __restrict__ bias,
    int N, int K, int nn,
    void* out0, const float* res, float* out1) {
  __shared__ alignas(16) unsigned short AsE[128 * 64];
  __shared__ alignas(16) unsigned short BsE[128 * 64];
  __shared__ alignas(16) unsigned short AsO[128 * 64];
  __shared__ alignas(16) unsigned short BsO[128 * 64];
  const int tid = threadIdx.x;
  const int lane = tid & 63;
  const int wave = tid >> 6;        // 0..3
  const int wr = wave >> 1;         // 0..1 row half (64 rows)
  const int wc = wave & 1;          // 0..1 col half (64 cols)
  int id = blockIdx.x;
  const int nwg = gridDim.x;
  id = (id & 7) * (nwg >> 3) + (id >> 3);   // XCD swizzle (grid % 8 == 0)
  const int bx = id % nn;
  const int by = id / nn;
  const int m0 = by * 128;
  const int n0 = bx * 128;
  const int ro = lane & 15;
  const int hi = lane >> 4;

  auto stA = [&](unsigned short* buf, int q, int kt) {   // 32-row quarter
    const int row = q * 32 + (tid >> 3);
    const int lc = (tid & 7) ^ (row & 7);
    gload16(A + (size_t)(m0 + row) * K + (size_t)kt * 64 + lc * 8,
            buf + q * 2048 + tid * 8);
  };
  auto stB = [&](unsigned short* buf, int q, int kt) {
    const int row = q * 32 + (tid >> 3);
    const int lc = (tid & 7) ^ (row & 7);
    gload16(Bw + (size_t)(n0 + row) * K + (size_t)kt * 64 + lc * 8,
            buf + q * 2048 + tid * 8);
  };

  f32x4 acc[4][4];
#pragma unroll
  for (int i = 0; i < 4; ++i)
#pragma unroll
    for (int j = 0; j < 4; ++j) acc[i][j] = f32x4{0.f, 0.f, 0.f, 0.f};

  bf16x8 af[2][2], bf[4][2];
  auto ldA = [&](const unsigned short* buf, int half) {  // half 0: mi 0,1
#pragma unroll
    for (int mi = 0; mi < 2; ++mi) {
      const int r = wr * 64 + (half * 2 + mi) * 16 + ro;
#pragma unroll
      for (int ks = 0; ks < 2; ++ks)
        af[mi][ks] = *(const bf16x8*)&buf[r * 64 + (((ks << 2) + hi) ^ (r & 7)) * 8];
    }
  };
  auto ldB = [&](const unsigned short* buf) {
#pragma unroll
    for (int nj = 0; nj < 4; ++nj) {
      const int r = wc * 64 + nj * 16 + ro;
#pragma unroll
      for (int ks = 0; ks < 2; ++ks)
        bf[nj][ks] = *(const bf16x8*)&buf[r * 64 + (((ks << 2) + hi) ^ (r & 7)) * 8];
    }
  };
  auto mmH = [&](int half) {
    __builtin_amdgcn_s_setprio(1);
#pragma unroll
    for (int ks = 0; ks < 2; ++ks)
#pragma unroll
      for (int mi = 0; mi < 2; ++mi)
#pragma unroll
        for (int nj = 0; nj < 4; ++nj)
          acc[half * 2 + mi][nj] =
              __builtin_amdgcn_mfma_f32_16x16x32_bf16(af[mi][ks], bf[nj][ks],
                                                      acc[half * 2 + mi][nj], 0, 0, 0);
    __builtin_amdgcn_s_setprio(0);
  };

  const int NT = K >> 6;     // even (K=1024 here)
  // prologue: E(t0) full; O(t1): A q0,q2 + B q0,q1 (rest staged at first P1)
  stA(AsE, 0, 0); stA(AsE, 1, 0); stA(AsE, 2, 0); stA(AsE, 3, 0);
  stB(BsE, 0, 0); stB(BsE, 1, 0); stB(BsE, 2, 0); stB(BsE, 3, 0);
  stA(AsO, 0, 1); stA(AsO, 2, 1);
  stB(BsO, 0, 1); stB(BsO, 1, 1);
  asm volatile("s_waitcnt vmcnt(0)" ::: "memory");
  SBAR();

  for (int t = 0; t < NT; t += 2) {
    const bool last = (t + 2 >= NT);
    // P1: A-low-E + all B-E
    ldA(AsE, 0); ldB(BsE);
    stB(BsO, 2, t + 1); stB(BsO, 3, t + 1);
    stA(AsO, 1, t + 1); stA(AsO, 3, t + 1);
    SBAR(); mmH(0); SBAR();
    // P2: A-high-E
    ldA(AsE, 1);
    if (!last) { stA(AsE, 0, t + 2); stA(AsE, 2, t + 2);
                 stB(BsE, 0, t + 2); stB(BsE, 1, t + 2); }
    if (!last) asm volatile("s_waitcnt vmcnt(4)" ::: "memory");
    else       asm volatile("s_waitcnt vmcnt(0)" ::: "memory");
    SBAR(); mmH(1); SBAR();
    // P3: A-low-O + all B-O
    ldA(AsO, 0); ldB(BsO);
    if (!last) { stA(AsE, 1, t + 2); stA(AsE, 3, t + 2);
                 stB(BsE, 2, t + 2); stB(BsE, 3, t + 2); }
    SBAR(); mmH(0); SBAR();
    // P4: A-high-O
    ldA(AsO, 1);
    if (!last) { stA(AsO, 0, t + 3); stA(AsO, 2, t + 3);
                 stB(BsO, 0, t + 3); stB(BsO, 1, t + 3); }
    if (!last) asm volatile("s_waitcnt vmcnt(4)" ::: "memory");
    SBAR(); mmH(1); SBAR();
  }

  const int r4 = hi * 4;
#pragma unroll
  for (int mi = 0; mi < 4; ++mi) {
#pragma unroll
    for (int nj = 0; nj < 4; ++nj) {
      const int cg = n0 + wc * 64 + nj * 16 + ro;
      const float bv = bias[cg];
#pragma unroll
      for (int q = 0; q < 4; ++q) {
        const int rg = m0 + wr * 64 + mi * 16 + r4 + q;
        const size_t idx = (size_t)rg * N + cg;
        const float v = acc[mi][nj][q] + bv;
        if (EPI == EPI_BF16) {
          ((unsigned short*)out0)[idx] = f2b(v);
        } else if (EPI == EPI_RELU_BF16) {
          ((unsigned short*)out0)[idx] = f2b(fmaxf(v, 0.f));
        } else if (EPI == EPI_RES) {
          ((float*)out0)[idx] = res[idx] + v;        // out may alias res
        } else {                                      // EPI_RES2
          const float r = res[idx];
          ((float*)out0)[idx] = v;                    // c = val
          out1[idx] = r + v;                          // x = x + val
        }
      }
    }
  }
}

// ---------------- fused flash attention (4-wave, LDS-staged K/V) ----------------

template<bool CAUSAL>
__global__ __launch_bounds__(256) void attn_kernel(
    const unsigned short* __restrict__ Qg, int qs,
    const unsigned short* __restrict__ Kg, int ksd,
    const unsigned short* __restrict__ Vt,
    unsigned short* __restrict__ Og) {
  __shared__ alignas(16) unsigned short Ks[2][64 * 64];
  __shared__ alignas(16) unsigned short Vs[2][64 * 64];
  __shared__ alignas(16) unsigned short Pl[4][32 * 64];
  const int qt0 = blockIdx.x;
  const int h  = blockIdx.y;
  const int b  = blockIdx.z;
  const int tid = threadIdx.x;
  const int lane = tid & 63;
  const int w = tid >> 6;
  const int ro = lane & 15;
  const int hi = lane >> 4;
  const int qrow0 = qt0 * 128 + w * 32;
  const size_t qbase = (size_t)b * 512 * qs  + (size_t)h * 64;
  const size_t kbase = (size_t)b * 512 * ksd + (size_t)h * 64;
  const size_t vbase = ((size_t)(b * 16 + h)) * 64 * 512;
  const size_t obase = (size_t)b * 512 * 1024 + (size_t)h * 64;

  bf16x8 qf[2][2];
#pragma unroll
  for (int mi = 0; mi < 2; ++mi)
#pragma unroll
    for (int ks = 0; ks < 2; ++ks)
      qf[mi][ks] = *(const bf16x8*)&Qg[qbase + (size_t)(qrow0 + mi * 16 + ro) * qs + ks * 32 + hi * 8];

  f32x4 o[2][4];
  float mrun[2][4], lrun[2][4];
#pragma unroll
  for (int mi = 0; mi < 2; ++mi) {
#pragma unroll
    for (int di = 0; di < 4; ++di) o[mi][di] = f32x4{0.f, 0.f, 0.f, 0.f};
#pragma unroll
    for (int q = 0; q < 4; ++q) { mrun[mi][q] = -1e30f; lrun[mi][q] = 0.f; }
  }

  auto stage = [&](int buf, int kt) {
#pragma unroll
    for (int i = 0; i < 2; ++i) {
      const int c = tid + 256 * i;
      const int row = c >> 3;
      const int lc = (c & 7) ^ (row & 7);
      gload16(Kg + kbase + (size_t)(kt * 64 + row) * ksd + lc * 8, &Ks[buf][c * 8]);
    }
#pragma unroll
    for (int i = 0; i < 2; ++i) {
      const int c = tid + 256 * i;
      const int row = c >> 3;
      const int lc = (c & 7) ^ (row & 7);
      gload16(Vt + vbase + (size_t)row * 512 + (size_t)kt * 64 + lc * 8, &Vs[buf][c * 8]);
    }
  };

  const int ktmax = CAUSAL ? (qt0 * 2 + 1) : 7;
  stage(0, 0);
  int cur = 0;
  for (int kt = 0; kt <= ktmax; ++kt) {
    __syncthreads();
    if (kt < ktmax) stage(cur ^ 1, kt + 1);
    const bool skip = CAUSAL && (kt * 64 > qrow0 + 31);
    if (!skip) {
      bf16x8 kf[4][2];
#pragma unroll
      for (int ni = 0; ni < 4; ++ni) {
        const int r = ni * 16 + ro;
#pragma unroll
        for (int ks = 0; ks < 2; ++ks)
          kf[ni][ks] = *(const bf16x8*)&Ks[cur][r * 64 + (((ks << 2) + hi) ^ (r & 7)) * 8];
      }

      f32x4 s[2][4];
#pragma unroll
      for (int mi = 0; mi < 2; ++mi)
#pragma unroll
        for (int ni = 0; ni < 4; ++ni) s[mi][ni] = f32x4{0.f, 0.f, 0.f, 0.f};
#pragma unroll
      for (int ks = 0; ks < 2; ++ks)
#pragma unroll
        for (int mi = 0; mi < 2; ++mi)
#pragma unroll
          for (int ni = 0; ni < 4; ++ni)
            s[mi][ni] = __builtin_amdgcn_mfma_f32_16x16x32_bf16(qf[mi][ks], kf[ni][ks], s[mi][ni], 0, 0, 0);

      const bool dm = CAUSAL && (kt * 64 + 63 > qrow0);
#pragma unroll
      for (int mi = 0; mi < 2; ++mi)
#pragma unroll
        for (int ni = 0; ni < 4; ++ni)
#pragma unroll
          for (int q = 0; q < 4; ++q) {
            float e = s[mi][ni][q] * 0.125f;
            if (dm && (kt * 64 + ni * 16 + ro) > (qrow0 + mi * 16 + hi * 4 + q)) e = -1e9f;
            s[mi][ni][q] = e;
          }

      float fac[2][4];
#pragma unroll
      for (int mi = 0; mi < 2; ++mi)
#pragma unroll
        for (int q = 0; q < 4; ++q) {
          float rm = s[mi][0][q];
#pragma unroll
          for (int ni = 1; ni < 4; ++ni) rm = fmaxf(rm, s[mi][ni][q]);
          rm = wred_max16(rm);
          const float mn = fmaxf(mrun[mi][q], rm);
          fac[mi][q] = __expf(mrun[mi][q] - mn);
          mrun[mi][q] = mn;
        }
#pragma unroll
      for (int mi = 0; mi < 2; ++mi)
#pragma unroll
        for (int q = 0; q < 4; ++q) {
          float rs = 0.f;
#pragma unroll
          for (int ni = 0; ni < 4; ++ni) {
            const float pv = __expf(s[mi][ni][q] - mrun[mi][q]);
            s[mi][ni][q] = pv;
            rs += pv;
          }
          rs = wred_sum16(rs);
          lrun[mi][q] = lrun[mi][q] * fac[mi][q] + rs;
        }
#pragma unroll
      for (int mi = 0; mi < 2; ++mi)
#pragma unroll
        for (int di = 0; di < 4; ++di)
#pragma unroll
          for (int q = 0; q < 4; ++q) o[mi][di][q] *= fac[mi][q];

#pragma unroll
      for (int mi = 0; mi < 2; ++mi)
#pragma unroll
        for (int ni = 0; ni < 4; ++ni)
#pragma unroll
          for (int q = 0; q < 4; ++q) {
            const int row = mi * 16 + hi * 4 + q;
            const int col = ni * 16 + ro;
            const int sc  = ((col >> 3) ^ (row & 7)) * 8 + (col & 7);
            Pl[w][row * 64 + sc] = f2b(s[mi][ni][q]);
          }

      bf16x8 pa[2][2];
#pragma unroll
      for (int mi = 0; mi < 2; ++mi)
#pragma unroll
        for (int ks = 0; ks < 2; ++ks) {
          const int row = mi * 16 + ro;
          pa[mi][ks] = *(const bf16x8*)&Pl[w][row * 64 + (((ks << 2) + hi) ^ (row & 7)) * 8];
        }

#pragma unroll
      for (int di = 0; di < 4; ++di)
#pragma unroll
        for (int ks = 0; ks < 2; ++ks) {
          const int r = di * 16 + ro;
          const bf16x8 vf = *(const bf16x8*)&Vs[cur][r * 64 + (((ks << 2) + hi) ^ (r & 7)) * 8];
#pragma unroll
          for (int mi = 0; mi < 2; ++mi)
            o[mi][di] = __builtin_amdgcn_mfma_f32_16x16x32_bf16(pa[mi][ks], vf, o[mi][di], 0, 0, 0);
        }
    }
    cur ^= 1;
  }

#pragma unroll
  for (int mi = 0; mi < 2; ++mi)
#pragma unroll
    for (int di = 0; di < 4; ++di)
#pragma unroll
      for (int q = 0; q < 4; ++q) {
        const float val = o[mi][di][q] / lrun[mi][q];
        Og[obase + (size_t)(qrow0 + mi * 16 + hi * 4 + q) * 1024 + di * 16 + ro] = f2b(val);
      }
}

// ---------------- host orchestration ----------------

extern "C" void kernel_launch(void* const* d_in, const int* in_sizes, int n_in,
                              void* d_out, int out_size, void* d_ws, size_t ws_size,
                              hipStream_t stream) {
  (void)in_sizes; (void)n_in; (void)out_size; (void)ws_size;
  const int*   dec = (const int*)d_in[0];
  const float* enc = (const float*)d_in[2];
  const float* emb = (const float*)d_in[4];
  const float* pe  = (const float*)d_in[5];
  const float* wq  = (const float*)d_in[6];
  const float* bq  = (const float*)d_in[7];
  const float* wk  = (const float*)d_in[8];
  const float* bk  = (const float*)d_in[9];
  const float* wv  = (const float*)d_in[10];
  const float* bv  = (const float*)d_in[11];
  const float* wo  = (const float*)d_in[12];
  const float* bo  = (const float*)d_in[13];
  const float* w1  = (const float*)d_in[14];
  const float* b1  = (const float*)d_in[15];
  const float* w2  = (const float*)d_in[16];
  const float* b2  = (const float*)d_in[17];
  const float* lng = (const float*)d_in[18];
  const float* lnb = (const float*)d_in[19];

  const size_t SZ_ACT = 4194304ull;     // 4096*1024

  char* p = (char*)d_ws;
  auto alloc = [&](size_t bytes) { char* r = p; p += (bytes + 255) & ~(size_t)255; return r; };
  unsigned short* qkvw  = (unsigned short*)alloc(3ull * 3 * 1048576 * 2);  // [L][3072][1024]
  unsigned short* kvw   = (unsigned short*)alloc(3ull * 2 * 1048576 * 2);  // [6144][1024]
  unsigned short* wqxb  = (unsigned short*)alloc(3ull * 1048576 * 2);      // [L][1024][1024]
  unsigned short* Wob   = (unsigned short*)alloc(6291456ull * 2);          // [L][2][1024][1024]
  unsigned short* W1b   = (unsigned short*)alloc(12582912ull * 2);
  unsigned short* W2b   = (unsigned short*)alloc(12582912ull * 2);
  unsigned short* encb  = (unsigned short*)alloc(SZ_ACT * 2);
  float*          x     = (float*)alloc(SZ_ACT * 4);
  float*          c     = (float*)alloc(SZ_ACT * 4);
  unsigned short* hb    = (unsigned short*)alloc(SZ_ACT * 2);
  unsigned short* qkvb  = (unsigned short*)alloc(4096ull * 3072 * 2);
  unsigned short* kvb   = (unsigned short*)alloc(4096ull * 6144 * 2);      // merged 3-layer K/V
  unsigned short* qb    = (unsigned short*)alloc(SZ_ACT * 2);
  unsigned short* vtbS  = (unsigned short*)alloc(SZ_ACT * 2);              // self V^T [B][H][64][512]
  unsigned short* vtb3  = (unsigned short*)alloc(3ull * SZ_ACT * 2);       // cross V^T per layer
  unsigned short* mid   = (unsigned short*)alloc(4096ull * 4096 * 2);
  float*          pbuf  = (float*)alloc(4ull * SZ_ACT * 4);                // split-K partials
  float*          qkvbias = (float*)alloc(3ull * 3072 * 4);
  float*          kvbias  = (float*)alloc(3ull * 2048 * 4);

  cvt_kernel<<<2048, 256, 0, stream>>>(wo, Wob, 1572864);
  cvt_kernel<<<2048, 256, 0, stream>>>(w1, W1b, 3145728);
  cvt_kernel<<<2048, 256, 0, stream>>>(w2, W2b, 3145728);
  cvt_kernel<<<2048, 256, 0, stream>>>(enc, encb, 1048576);
  pack_w<<<dim3(1024, 3, 3), 256, 0, stream>>>(wq, wk, wv, 0, qkvw, 3);
  pack_w<<<dim3(1024, 2, 3), 256, 0, stream>>>(wk, wv, wv, 1, kvw, 2);
  pack_w<<<dim3(1024, 1, 3), 256, 0, stream>>>(wq, wq, wq, 1, wqxb, 1);
  pack_bias<<<dim3(3, 3), 256, 0, stream>>>(bq, bk, bv, 0, qkvbias, 3);
  pack_bias<<<dim3(2, 3), 256, 0, stream>>>(bk, bv, bv, 1, kvbias, 2);
  embed_kernel<<<4096, 256, 0, stream>>>(dec, emb, pe, x);

  // merged cross-attn K/V for all 3 layers; V written transposed to vtb3[l]
  gemm8p<0, 2><<<16 * 24, 512, 0, stream>>>(encb, kvw, kvbias, 6144, kvb, vtb3);

  const dim3 gAttn(4, 16, 8);

  for (int l = 0; l < 3; ++l) {
    const float* g0 = lng + (l * 3 + 0) * 1024; const float* e0 = lnb + (l * 3 + 0) * 1024;
    const float* g1 = lng + (l * 3 + 1) * 1024; const float* e1 = lnb + (l * 3 + 1) * 1024;
    const float* g2 = lng + (l * 3 + 2) * 1024; const float* e2 = lnb + (l * 3 + 2) * 1024;

    // ---- self-attention sublayer ----
    if (l == 0)
      ln_kernel<<<4096, 64, 0, stream>>>(x, g0, e0, hb);
    // (for l=1,2 hb was produced by reduce4_ln of the previous layer)
    gemm8p<0, 1><<<16 * 12, 512, 0, stream>>>(hb, qkvw + (size_t)l * 3 * 1048576,
        qkvbias + l * 3072, 3072, qkvb, vtbS);
    attn_kernel<true><<<gAttn, 256, 0, stream>>>(qkvb, 3072, qkvb + 1024, 3072, vtbS, hb);
    gemm_s8<EPI_RES><<<32 * 8, 256, 0, stream>>>(hb, Wob + (size_t)(l * 2) * 1048576,
        bo + (l * 2) * 1024, 1024, 1024, 8, x, x, nullptr);

    // ---- cross-attention sublayer ----
    ln_kernel<<<4096, 64, 0, stream>>>(x, g1, e1, hb);
    gemm_s8<EPI_BF16><<<32 * 8, 256, 0, stream>>>(hb, wqxb + (size_t)l * 1048576,
        bq + (l * 2 + 1) * 1024, 1024, 1024, 8, qb, nullptr, nullptr);
    attn_kernel<false><<<gAttn, 256, 0, stream>>>(qb, 1024, kvb + l * 2048, 6144,
        vtb3 + (size_t)l * SZ_ACT, hb);
    gemm_s8<EPI_RES2><<<32 * 8, 256, 0, stream>>>(hb, Wob + (size_t)(l * 2 + 1) * 1048576,
        bo + (l * 2 + 1) * 1024, 1024, 1024, 8, c, x, x);

    // ---- FFN sublayer (residual is c, per reference quirk) ----
    ln_kernel<<<4096, 64, 0, stream>>>(x, g2, e2, hb);
    gemm8p<1, 0><<<16 * 16, 512, 0, stream>>>(hb, W1b + (size_t)l * 4194304,
        b1 + l * 4096, 4096, mid, nullptr);
    gemm_sk8<<<256, 512, 0, stream>>>(mid, W2b + (size_t)l * 4194304, pbuf);
    if (l == 2) {
      reduce4_kernel<<<2048, 256, 0, stream>>>(c, pbuf, b2 + l * 1024, (float*)d_out);
    } else {
      // fused: x = c + sum(p) + b2;  hb = LN(x) with NEXT layer's norm1 params
      const float* gn = lng + ((l + 1) * 3 + 0) * 1024;
      const float* en = lnb + ((l + 1) * 3 + 0) * 1024;
      reduce4_ln_kernel<<<4096, 64, 0, stream>>>(c, pbuf, b2 + l * 1024, gn, en, x, hb);
    }
  }
}

// Round 20
// 1072.227 us; speedup vs baseline: 1.0380x; 1.0380x over previous
//
#include <hip/hip_runtime.h>
#include <hip/hip_bf16.h>

using bf16x8 = __attribute__((ext_vector_type(8))) short;
using f32x4  = __attribute__((ext_vector_type(4))) float;
using u16x4  = __attribute__((ext_vector_type(4))) unsigned short;

#define DEVI static __device__ __forceinline__
#define SBAR() asm volatile("s_barrier" ::: "memory")

DEVI unsigned short f2b(float f) {           // f32 -> bf16 RNE
  unsigned int u = __float_as_uint(f);
  u += 0x7FFFu + ((u >> 16) & 1u);
  return (unsigned short)(u >> 16);
}

DEVI void gload16(const unsigned short* g, unsigned short* l) {
  __builtin_amdgcn_global_load_lds(
      (const __attribute__((address_space(1))) unsigned int*)g,
      (__attribute__((address_space(3))) unsigned int*)l, 16, 0, 0);
}

DEVI float wred_max16(float v) {
#pragma unroll
  for (int m = 1; m < 16; m <<= 1) v = fmaxf(v, __shfl_xor(v, m, 64));
  return v;
}
DEVI float wred_sum16(float v) {
#pragma unroll
  for (int m = 1; m < 16; m <<= 1) v += __shfl_xor(v, m, 64);
  return v;
}

// ---------------- elementwise / pack kernels ----------------

__global__ void cvt_kernel(const float* __restrict__ in,
                           unsigned short* __restrict__ out, int n4) {
  int i = blockIdx.x * blockDim.x + threadIdx.x;
  const int stride = gridDim.x * blockDim.x;
  for (; i < n4; i += stride) {
    const float4 v = ((const float4*)in)[i];
    u16x4 o;
    o[0] = f2b(v.x); o[1] = f2b(v.y); o[2] = f2b(v.z); o[3] = f2b(v.w);
    ((u16x4*)out)[i] = o;
  }
}

__global__ void pack_w(const float* __restrict__ s0,
                       const float* __restrict__ s1,
                       const float* __restrict__ s2,
                       int sub, unsigned short* __restrict__ dst, int nm) {
  const int r = blockIdx.x;
  const int m = blockIdx.y;
  const int l = blockIdx.z;
  const float* src = (m == 0 ? s0 : m == 1 ? s1 : s2)
                   + (size_t)(l * 2 + sub) * 1048576 + (size_t)r * 1024;
  unsigned short* d = dst + ((size_t)(l * nm + m) * 1024 + r) * 1024;
  const int col = threadIdx.x * 4;
  const float4 v = *(const float4*)(src + col);
  u16x4 o;
  o[0] = f2b(v.x); o[1] = f2b(v.y); o[2] = f2b(v.z); o[3] = f2b(v.w);
  *(u16x4*)(d + col) = o;
}

__global__ void pack_bias(const float* __restrict__ s0,
                          const float* __restrict__ s1,
                          const float* __restrict__ s2,
                          int sub, float* __restrict__ dst, int nm) {
  const int m = blockIdx.x, l = blockIdx.y;
  const float* src = (m == 0 ? s0 : m == 1 ? s1 : s2) + (size_t)(l * 2 + sub) * 1024;
  float* d = dst + ((size_t)l * nm + m) * 1024;
  const int i = threadIdx.x * 4;
  *(float4*)(d + i) = *(const float4*)(src + i);
}

__global__ void embed_kernel(const int* __restrict__ ids,
                             const float* __restrict__ emb,
                             const float* __restrict__ pe,
                             float* __restrict__ x) {
  const int row = blockIdx.x;
  const int t = row & 511;
  const int col = threadIdx.x * 4;
  const int id = ids[row];
  const float4 e = *(const float4*)(emb + (size_t)id * 1024 + col);
  const float4 p = *(const float4*)(pe + (size_t)t * 1024 + col);
  float4 o;
  o.x = e.x * 32.f + p.x; o.y = e.y * 32.f + p.y;
  o.z = e.z * 32.f + p.z; o.w = e.w * 32.f + p.w;
  *(float4*)(x + (size_t)row * 1024 + col) = o;
}

__global__ void ln_kernel(const float* __restrict__ x,
                          const float* __restrict__ g,
                          const float* __restrict__ b,
                          unsigned short* __restrict__ out) {
  const int row = blockIdx.x;
  const int l = threadIdx.x;
  const float4* xr = (const float4*)(x + (size_t)row * 1024);
  float4 v[4];
  float s = 0.f;
#pragma unroll
  for (int i = 0; i < 4; ++i) {
    v[i] = xr[l * 4 + i];
    s += v[i].x + v[i].y + v[i].z + v[i].w;
  }
#pragma unroll
  for (int m = 1; m < 64; m <<= 1) s += __shfl_xor(s, m, 64);
  const float mean = s * (1.f / 1024.f);
  float vs = 0.f;
#pragma unroll
  for (int i = 0; i < 4; ++i) {
    float dx = v[i].x - mean, dy = v[i].y - mean, dz = v[i].z - mean, dw = v[i].w - mean;
    vs += dx * dx + dy * dy + dz * dz + dw * dw;
  }
#pragma unroll
  for (int m = 1; m < 64; m <<= 1) vs += __shfl_xor(vs, m, 64);
  const float inv = rsqrtf(vs * (1.f / 1024.f) + 1e-5f);
#pragma unroll
  for (int i = 0; i < 4; ++i) {
    const int col = l * 16 + i * 4;
    const float4 gg = *(const float4*)(g + col);
    const float4 bb = *(const float4*)(b + col);
    u16x4 o;
    o[0] = f2b((v[i].x - mean) * inv * gg.x + bb.x);
    o[1] = f2b((v[i].y - mean) * inv * gg.y + bb.y);
    o[2] = f2b((v[i].z - mean) * inv * gg.z + bb.z);
    o[3] = f2b((v[i].w - mean) * inv * gg.w + bb.w);
    *(u16x4*)(out + (size_t)row * 1024 + col) = o;
  }
}

// Fused FFN2 reduce + next LayerNorm (layers 0,1):
// x = c + p0+p1+p2+p3 + bias;  hb = bf16(LN(x)*g + e)
__global__ void reduce4_ln_kernel(const float* __restrict__ c,
                                  const float* __restrict__ pbuf,
                                  const float* __restrict__ bias,
                                  const float* __restrict__ g,
                                  const float* __restrict__ e,
                                  float* __restrict__ x,
                                  unsigned short* __restrict__ hb) {
  const int row = blockIdx.x;
  const int l = threadIdx.x;            // 64 lanes, 16 elems each
  const size_t base = (size_t)row * 1024;
  const float4* cc = (const float4*)(c + base);
  const float4* p0 = (const float4*)(pbuf + base);
  const float4* p1 = (const float4*)(pbuf + 4194304 + base);
  const float4* p2 = (const float4*)(pbuf + 2 * 4194304 + base);
  const float4* p3 = (const float4*)(pbuf + 3 * 4194304 + base);
  float4 v[4];
  float s = 0.f;
#pragma unroll
  for (int i = 0; i < 4; ++i) {
    const int fi = l * 4 + i;
    const float4 a = cc[fi];
    const float4 b0 = p0[fi], b1 = p1[fi], b2v = p2[fi], b3 = p3[fi];
    const float4 bb = ((const float4*)bias)[fi & 255];
    float4 o;
    o.x = a.x + (b0.x + b1.x) + (b2v.x + b3.x) + bb.x;
    o.y = a.y + (b0.y + b1.y) + (b2v.y + b3.y) + bb.y;
    o.z = a.z + (b0.z + b1.z) + (b2v.z + b3.z) + bb.z;
    o.w = a.w + (b0.w + b1.w) + (b2v.w + b3.w) + bb.w;
    v[i] = o;
    s += o.x + o.y + o.z + o.w;
    *(float4*)(x + base + fi * 4) = o;
  }
#pragma unroll
  for (int m = 1; m < 64; m <<= 1) s += __shfl_xor(s, m, 64);
  const float mean = s * (1.f / 1024.f);
  float vs = 0.f;
#pragma unroll
  for (int i = 0; i < 4; ++i) {
    float dx = v[i].x - mean, dy = v[i].y - mean, dz = v[i].z - mean, dw = v[i].w - mean;
    vs += dx * dx + dy * dy + dz * dz + dw * dw;
  }
#pragma unroll
  for (int m = 1; m < 64; m <<= 1) vs += __shfl_xor(vs, m, 64);
  const float inv = rsqrtf(vs * (1.f / 1024.f) + 1e-5f);
#pragma unroll
  for (int i = 0; i < 4; ++i) {
    const int col = l * 16 + i * 4;
    const float4 gg = *(const float4*)(g + col);
    const float4 bb = *(const float4*)(e + col);
    u16x4 o;
    o[0] = f2b((v[i].x - mean) * inv * gg.x + bb.x);
    o[1] = f2b((v[i].y - mean) * inv * gg.y + bb.y);
    o[2] = f2b((v[i].z - mean) * inv * gg.z + bb.z);
    o[3] = f2b((v[i].w - mean) * inv * gg.w + bb.w);
    *(u16x4*)(hb + base + col) = o;
  }
}

// ------------- 8-phase fat GEMM core: 256x256 tile, 8 waves (m201 port) -------------

template<int LDA, int LDB>
DEVI void gemm8p_core(const unsigned short* __restrict__ A,
                      const unsigned short* __restrict__ Bw,
                      int m0, int n0, int kofs,
                      unsigned short* AsE, unsigned short* BsE,
                      unsigned short* AsO, unsigned short* BsO,
                      int tid, f32x4 (&acc)[8][4]) {
  constexpr int NT = 16;
  const int lane = tid & 63;
  const int wave = tid >> 6;
  const int wr = wave >> 2;
  const int wc = wave & 3;
  const int ro = lane & 15;
  const int hi = lane >> 4;

  auto stA = [&](unsigned short* buf, int q, int kt) {
    const int row = tid >> 3;
    const int lc = (tid & 7) ^ (row & 7);
    gload16(A + (size_t)(m0 + q * 64 + row) * LDA + kofs + kt * 64 + lc * 8,
            buf + q * 4096 + tid * 8);
  };
  auto stB = [&](unsigned short* buf, int q, int kt) {
    const int row = tid >> 3;
    const int lc = (tid & 7) ^ (row & 7);
    gload16(Bw + (size_t)(n0 + q * 64 + row) * LDB + kofs + kt * 64 + lc * 8,
            buf + q * 4096 + tid * 8);
  };

  bf16x8 af[4][2], bfL[2][2], bfR[2][2];
  auto ldAL = [&](const unsigned short* buf) {
#pragma unroll
    for (int mi = 0; mi < 4; ++mi) {
      const int r = wr * 128 + mi * 16 + ro;
#pragma unroll
      for (int ks = 0; ks < 2; ++ks)
        af[mi][ks] = *(const bf16x8*)&buf[r * 64 + (((ks << 2) + hi) ^ (r & 7)) * 8];
    }
  };
  auto ldAH = [&](const unsigned short* buf) {
#pragma unroll
    for (int mi = 0; mi < 4; ++mi) {
      const int r = wr * 128 + 64 + mi * 16 + ro;
#pragma unroll
      for (int ks = 0; ks < 2; ++ks)
        af[mi][ks] = *(const bf16x8*)&buf[r * 64 + (((ks << 2) + hi) ^ (r & 7)) * 8];
    }
  };
  auto ldBL = [&](const unsigned short* buf) {
#pragma unroll
    for (int nj = 0; nj < 2; ++nj) {
      const int r = wc * 64 + nj * 16 + ro;
#pragma unroll
      for (int ks = 0; ks < 2; ++ks)
        bfL[nj][ks] = *(const bf16x8*)&buf[r * 64 + (((ks << 2) + hi) ^ (r & 7)) * 8];
    }
  };
  auto ldBR = [&](const unsigned short* buf) {
#pragma unroll
    for (int nj = 0; nj < 2; ++nj) {
      const int r = wc * 64 + 32 + nj * 16 + ro;
#pragma unroll
      for (int ks = 0; ks < 2; ++ks)
        bfR[nj][ks] = *(const bf16x8*)&buf[r * 64 + (((ks << 2) + hi) ^ (r & 7)) * 8];
    }
  };
  auto mmQ = [&](bf16x8 (&bf)[2][2], int mo, int no) {
    __builtin_amdgcn_s_setprio(1);
#pragma unroll
    for (int ks = 0; ks < 2; ++ks)
#pragma unroll
      for (int mi = 0; mi < 4; ++mi)
#pragma unroll
        for (int nj = 0; nj < 2; ++nj)
          acc[mo + mi][no + nj] =
              __builtin_amdgcn_mfma_f32_16x16x32_bf16(af[mi][ks], bf[nj][ks],
                                                      acc[mo + mi][no + nj], 0, 0, 0);
    __builtin_amdgcn_s_setprio(0);
  };

  stA(AsE, 0, 0); stA(AsE, 1, 0); stA(AsE, 2, 0); stA(AsE, 3, 0);
  stB(BsE, 0, 0); stB(BsE, 1, 0); stB(BsE, 2, 0); stB(BsE, 3, 0);
  stA(AsO, 0, 1); stA(AsO, 1, 1); stA(AsO, 2, 1); stA(AsO, 3, 1);
  stB(BsO, 0, 1); stB(BsO, 1, 1);
  asm volatile("s_waitcnt vmcnt(0)" ::: "memory");
  SBAR();

  for (int t = 0; t < NT; t += 2) {
    const bool last = (t + 2 >= NT);
    ldAL(AsE); ldBL(BsE);
    stB(BsO, 2, t + 1); stB(BsO, 3, t + 1);
    SBAR(); mmQ(bfL, 0, 0); SBAR();
    ldBR(BsE);
    if (!last) { stA(AsE, 0, t + 2); stA(AsE, 2, t + 2); }
    SBAR(); mmQ(bfR, 0, 2); SBAR();
    ldAH(AsE);
    if (!last) { stB(BsE, 0, t + 2); stB(BsE, 1, t + 2); }
    SBAR(); mmQ(bfL, 4, 0); SBAR();
    if (!last) {
      stA(AsE, 1, t + 2); stA(AsE, 3, t + 2);
      asm volatile("s_waitcnt vmcnt(6)" ::: "memory");
    } else {
      asm volatile("s_waitcnt vmcnt(0)" ::: "memory");
    }
    SBAR(); mmQ(bfR, 4, 2); SBAR();
    ldAL(AsO); ldBL(BsO);
    if (!last) { stB(BsE, 2, t + 2); stB(BsE, 3, t + 2); }
    SBAR(); mmQ(bfL, 0, 0); SBAR();
    ldBR(BsO);
    if (!last) { stA(AsO, 0, t + 3); stA(AsO, 2, t + 3); }
    SBAR(); mmQ(bfR, 0, 2); SBAR();
    ldAH(AsO);
    if (!last) { stB(BsO, 0, t + 3); stB(BsO, 1, t + 3); }
    SBAR(); mmQ(bfL, 4, 0); SBAR();
    if (!last) {
      stA(AsO, 1, t + 3); stA(AsO, 3, t + 3);
      asm volatile("s_waitcnt vmcnt(6)" ::: "memory");
    }
    SBAR(); mmQ(bfR, 4, 2); SBAR();
  }
}

// VT = 0: plain.  VT = 1: self-QKV (N=3072) — cols >=2048 are V, written ONLY
// transposed into vt[b][h][64][512].  VT = 2: merged KV (N=6144) — cols with
// (cg & 2047) >= 1024 are layer cg>>11's V, written only transposed into
// vt + layer*4194304. V-tile boundaries are 256-aligned -> block-uniform.
template<int EPI, int VT>
__global__ __launch_bounds__(512, 1) void gemm8p(
    const unsigned short* __restrict__ A,
    const unsigned short* __restrict__ Bw,
    const float* __restrict__ bias,
    int N, unsigned short* __restrict__ out0,
    unsigned short* __restrict__ vt) {
  __shared__ alignas(16) unsigned short AsE[256 * 64];
  __shared__ alignas(16) unsigned short BsE[256 * 64];
  __shared__ alignas(16) unsigned short AsO[256 * 64];
  __shared__ alignas(16) unsigned short BsO[256 * 64];
  const int tid = threadIdx.x;
  int id = blockIdx.x;
  const int nwg = gridDim.x;
  id = (id & 7) * (nwg >> 3) + (id >> 3);
  const int nn = N >> 8;
  const int bx = id % nn;
  const int by = id / nn;
  const int m0 = by * 256;
  const int n0 = bx * 256;

  f32x4 acc[8][4];
#pragma unroll
  for (int i = 0; i < 8; ++i)
#pragma unroll
    for (int j = 0; j < 4; ++j) acc[i][j] = f32x4{0.f, 0.f, 0.f, 0.f};

  gemm8p_core<1024, 1024>(A, Bw, m0, n0, 0, AsE, BsE, AsO, BsO, tid, acc);

  const int lane = tid & 63;
  const int wave = tid >> 6;
  const int wr = wave >> 2, wc = wave & 3;
  const int ro = lane & 15, hi = lane >> 4;
  const int r4 = hi * 4;
#pragma unroll
  for (int mi = 0; mi < 8; ++mi) {
#pragma unroll
    for (int nj = 0; nj < 4; ++nj) {
      const int cg = n0 + wc * 64 + nj * 16 + ro;
      const float bv = bias[cg];
      const int rg0 = m0 + wr * 128 + mi * 16 + r4;
      const bool isV1 = (VT == 1) && (cg >= 2048);
      const bool isV2 = (VT == 2) && ((cg & 2047) >= 1024);
      if (isV1 || isV2) {
        u16x4 o;
#pragma unroll
        for (int q = 0; q < 4; ++q) o[q] = f2b(acc[mi][nj][q] + bv);
        const int b = rg0 >> 9, t = rg0 & 511;
        size_t dst;
        if (isV1) {
          const int hh = (cg - 2048) >> 6, d = (cg - 2048) & 63;
          dst = (((size_t)(b * 16 + hh) * 64 + d) << 9) + t;
        } else {
          const int layer = cg >> 11;
          const int cm = (cg & 2047) - 1024;
          dst = (size_t)layer * 4194304 +
                (((size_t)(b * 16 + (cm >> 6)) * 64 + (cm & 63)) << 9) + t;
        }
        *(u16x4*)&vt[dst] = o;
      } else {
#pragma unroll
        for (int q = 0; q < 4; ++q) {
          const float v = acc[mi][nj][q] + bv;
          out0[(size_t)(rg0 + q) * N + cg] = f2b(EPI == 1 ? fmaxf(v, 0.f) : v);
        }
      }
    }
  }
}

// FFN2 split-K=4 on the 8-phase engine: writes f32 partials pbuf[s][4096][1024].
__global__ __launch_bounds__(512, 1) void gemm_sk8(
    const unsigned short* __restrict__ A,
    const unsigned short* __restrict__ Bw,
    float* __restrict__ pbuf) {
  __shared__ alignas(16) unsigned short AsE[256 * 64];
  __shared__ alignas(16) unsigned short BsE[256 * 64];
  __shared__ alignas(16) unsigned short AsO[256 * 64];
  __shared__ alignas(16) unsigned short BsO[256 * 64];
  const int tid = threadIdx.x;
  int id = blockIdx.x;
  const int nwg = gridDim.x;               // 256
  id = (id & 7) * (nwg >> 3) + (id >> 3);  // XCD swizzle
  const int s  = id >> 6;                  // split 0..3
  const int r6 = id & 63;
  const int bx = r6 & 3;                   // 4 col tiles (N=1024)
  const int by = r6 >> 2;                  // 16 row tiles
  const int m0 = by * 256;
  const int n0 = bx * 256;

  f32x4 acc[8][4];
#pragma unroll
  for (int i = 0; i < 8; ++i)
#pragma unroll
    for (int j = 0; j < 4; ++j) acc[i][j] = f32x4{0.f, 0.f, 0.f, 0.f};

  gemm8p_core<4096, 4096>(A, Bw, m0, n0, s * 1024, AsE, BsE, AsO, BsO, tid, acc);

  float* out = pbuf + (size_t)s * 4096 * 1024;
  const int lane = tid & 63;
  const int wave = tid >> 6;
  const int wr = wave >> 2, wc = wave & 3;
  const int ro = lane & 15, hi = lane >> 4;
  const int r4 = hi * 4;
#pragma unroll
  for (int mi = 0; mi < 8; ++mi)
#pragma unroll
    for (int nj = 0; nj < 4; ++nj) {
      const int cg = n0 + wc * 64 + nj * 16 + ro;
#pragma unroll
      for (int q = 0; q < 4; ++q) {
        const int rg = m0 + wr * 128 + mi * 16 + r4 + q;
        out[(size_t)rg * 1024 + cg] = acc[mi][nj][q];
      }
    }
}

// xout = c + p0 + p1 + p2 + p3 + bias   (f32, vectorized; used for l=2)
__global__ void reduce4_kernel(const float* __restrict__ c,
                               const float* __restrict__ pbuf,
                               const float* __restrict__ bias,
                               float* __restrict__ xout) {
  const int n4 = 4096 * 1024 / 4;
  int i = blockIdx.x * blockDim.x + threadIdx.x;
  const int stride = gridDim.x * blockDim.x;
  const float4* p0 = (const float4*)pbuf;
  const float4* p1 = (const float4*)(pbuf + 4194304);
  const float4* p2 = (const float4*)(pbuf + 2 * 4194304);
  const float4* p3 = (const float4*)(pbuf + 3 * 4194304);
  for (; i < n4; i += stride) {
    const float4 cc = ((const float4*)c)[i];
    const float4 a0 = p0[i];
    const float4 a1 = p1[i];
    const float4 a2 = p2[i];
    const float4 a3 = p3[i];
    const float4 bb = ((const float4*)bias)[i & 255];
    float4 o;
    o.x = cc.x + (a0.x + a1.x) + (a2.x + a3.x) + bb.x;
    o.y = cc.y + (a0.y + a1.y) + (a2.y + a3.y) + bb.y;
    o.z = cc.z + (a0.z + a1.z) + (a2.z + a3.z) + bb.z;
    o.w = cc.w + (a0.w + a1.w) + (a2.w + a3.w) + bb.w;
    ((float4*)xout)[i] = o;
  }
}

// ---------------- skinny GEMM (R7 structure, BM=128, BN=64) ----------------

enum { EPI_BF16 = 0, EPI_RELU_BF16 = 1, EPI_RES = 2, EPI_RES2 = 3 };

template<int EPI, int BM, int BN>
__global__ void gemm_bt(const unsigned short* __restrict__ A,
                        const unsigned short* __restrict__ Bw,
                        const float* __restrict__ bias,
                        int N, int K, int nn,
                        void* out0, const float* res, float* out1) {
  constexpr int MI = BM / 32;
  constexpr int NJ = BN / 32;
  __shared__ alignas(16) unsigned short As[2][BM * 64];
  __shared__ alignas(16) unsigned short Bs[2][BN * 64];
  const int tid = threadIdx.x;
  const int lane = tid & 63;
  const int wave = tid >> 6;
  int id = blockIdx.x;
  const int nwg = gridDim.x;
  id = (id & 7) * (nwg >> 3) + (id >> 3);
  const int bx = id % nn;
  const int by = id / nn;
  const int m0 = by * BM;
  const int n0 = bx * BN;
  const int wm = (wave >> 1) * (BM / 2);
  const int wn = (wave & 1) * (BN / 2);

  auto stage = [&](int buf, int kt) {
    const size_t k0 = (size_t)kt * 64;
#pragma unroll
    for (int i = 0; i < MI; ++i) {
      const int c = tid + 256 * i;
      const int row = c >> 3;
      const int lc = (c & 7) ^ (row & 7);
      gload16(A + (size_t)(m0 + row) * K + k0 + lc * 8, &As[buf][c * 8]);
    }
#pragma unroll
    for (int i = 0; i < NJ; ++i) {
      const int c = tid + 256 * i;
      const int row = c >> 3;
      const int lc = (c & 7) ^ (row & 7);
      gload16(Bw + (size_t)(n0 + row) * K + k0 + lc * 8, &Bs[buf][c * 8]);
    }
  };

  f32x4 acc[MI][NJ];
#pragma unroll
  for (int i = 0; i < MI; ++i)
#pragma unroll
    for (int j = 0; j < NJ; ++j) acc[i][j] = f32x4{0.f, 0.f, 0.f, 0.f};

  const int nk = K >> 6;
  stage(0, 0);
  int cur = 0;
  const int ro = lane & 15;
  const int hi = lane >> 4;
  for (int kt = 0; kt < nk; ++kt) {
    __syncthreads();
    if (kt + 1 < nk) stage(cur ^ 1, kt + 1);
    bf16x8 af[MI][2], bf[NJ][2];
#pragma unroll
    for (int i = 0; i < MI; ++i) {
      const int r = wm + i * 16 + ro;
#pragma unroll
      for (int ks = 0; ks < 2; ++ks)
        af[i][ks] = *(const bf16x8*)&As[cur][r * 64 + (((ks << 2) + hi) ^ (r & 7)) * 8];
    }
#pragma unroll
    for (int j = 0; j < NJ; ++j) {
      const int r = wn + j * 16 + ro;
#pragma unroll
      for (int ks = 0; ks < 2; ++ks)
        bf[j][ks] = *(const bf16x8*)&Bs[cur][r * 64 + (((ks << 2) + hi) ^ (r & 7)) * 8];
    }
#pragma unroll
    for (int ks = 0; ks < 2; ++ks)
#pragma unroll
      for (int i = 0; i < MI; ++i)
#pragma unroll
        for (int j = 0; j < NJ; ++j)
          acc[i][j] = __builtin_amdgcn_mfma_f32_16x16x32_bf16(af[i][ks], bf[j][ks], acc[i][j], 0, 0, 0);
    cur ^= 1;
  }

  const int r4 = hi * 4;
#pragma unroll
  for (int i = 0; i < MI; ++i) {
#pragma unroll
    for (int j = 0; j < NJ; ++j) {
      const int cg = n0 + wn + j * 16 + ro;
      const float bv = bias[cg];
#pragma unroll
      for (int q = 0; q < 4; ++q) {
        const int rg = m0 + wm + i * 16 + r4 + q;
        const size_t idx = (size_t)rg * N + cg;
        const float v = acc[i][j][q] + bv;
        if (EPI == EPI_BF16) {
          ((unsigned short*)out0)[idx] = f2b(v);
        } else if (EPI == EPI_RELU_BF16) {
          ((unsigned short*)out0)[idx] = f2b(fmaxf(v, 0.f));
        } else if (EPI == EPI_RES) {
          ((float*)out0)[idx] = res[idx] + v;
        } else {
          const float r = res[idx];
          ((float*)out0)[idx] = v;
          out1[idx] = r + v;
        }
      }
    }
  }
}

// ---------------- fused flash attention (4-wave, LDS-staged K/V) ----------------

template<bool CAUSAL>
__global__ __launch_bounds__(256) void attn_kernel(
    const unsigned short* __restrict__ Qg, int qs,
    const unsigned short* __restrict__ Kg, int ksd,
    const unsigned short* __restrict__ Vt,
    unsigned short* __restrict__ Og) {
  __shared__ alignas(16) unsigned short Ks[2][64 * 64];
  __shared__ alignas(16) unsigned short Vs[2][64 * 64];
  __shared__ alignas(16) unsigned short Pl[4][32 * 64];
  const int qt0 = blockIdx.x;
  const int h  = blockIdx.y;
  const int b  = blockIdx.z;
  const int tid = threadIdx.x;
  const int lane = tid & 63;
  const int w = tid >> 6;
  const int ro = lane & 15;
  const int hi = lane >> 4;
  const int qrow0 = qt0 * 128 + w * 32;
  const size_t qbase = (size_t)b * 512 * qs  + (size_t)h * 64;
  const size_t kbase = (size_t)b * 512 * ksd + (size_t)h * 64;
  const size_t vbase = ((size_t)(b * 16 + h)) * 64 * 512;
  const size_t obase = (size_t)b * 512 * 1024 + (size_t)h * 64;

  bf16x8 qf[2][2];
#pragma unroll
  for (int mi = 0; mi < 2; ++mi)
#pragma unroll
    for (int ks = 0; ks < 2; ++ks)
      qf[mi][ks] = *(const bf16x8*)&Qg[qbase + (size_t)(qrow0 + mi * 16 + ro) * qs + ks * 32 + hi * 8];

  f32x4 o[2][4];
  float mrun[2][4], lrun[2][4];
#pragma unroll
  for (int mi = 0; mi < 2; ++mi) {
#pragma unroll
    for (int di = 0; di < 4; ++di) o[mi][di] = f32x4{0.f, 0.f, 0.f, 0.f};
#pragma unroll
    for (int q = 0; q < 4; ++q) { mrun[mi][q] = -1e30f; lrun[mi][q] = 0.f; }
  }

  auto stage = [&](int buf, int kt) {
#pragma unroll
    for (int i = 0; i < 2; ++i) {
      const int c = tid + 256 * i;
      const int row = c >> 3;
      const int lc = (c & 7) ^ (row & 7);
      gload16(Kg + kbase + (size_t)(kt * 64 + row) * ksd + lc * 8, &Ks[buf][c * 8]);
    }
#pragma unroll
    for (int i = 0; i < 2; ++i) {
      const int c = tid + 256 * i;
      const int row = c >> 3;
      const int lc = (c & 7) ^ (row & 7);
      gload16(Vt + vbase + (size_t)row * 512 + (size_t)kt * 64 + lc * 8, &Vs[buf][c * 8]);
    }
  };

  const int ktmax = CAUSAL ? (qt0 * 2 + 1) : 7;
  stage(0, 0);
  int cur = 0;
  for (int kt = 0; kt <= ktmax; ++kt) {
    __syncthreads();
    if (kt < ktmax) stage(cur ^ 1, kt + 1);
    const bool skip = CAUSAL && (kt * 64 > qrow0 + 31);
    if (!skip) {
      bf16x8 kf[4][2];
#pragma unroll
      for (int ni = 0; ni < 4; ++ni) {
        const int r = ni * 16 + ro;
#pragma unroll
        for (int ks = 0; ks < 2; ++ks)
          kf[ni][ks] = *(const bf16x8*)&Ks[cur][r * 64 + (((ks << 2) + hi) ^ (r & 7)) * 8];
      }

      f32x4 s[2][4];
#pragma unroll
      for (int mi = 0; mi < 2; ++mi)
#pragma unroll
        for (int ni = 0; ni < 4; ++ni) s[mi][ni] = f32x4{0.f, 0.f, 0.f, 0.f};
#pragma unroll
      for (int ks = 0; ks < 2; ++ks)
#pragma unroll
        for (int mi = 0; mi < 2; ++mi)
#pragma unroll
          for (int ni = 0; ni < 4; ++ni)
            s[mi][ni] = __builtin_amdgcn_mfma_f32_16x16x32_bf16(qf[mi][ks], kf[ni][ks], s[mi][ni], 0, 0, 0);

      const bool dm = CAUSAL && (kt * 64 + 63 > qrow0);
#pragma unroll
      for (int mi = 0; mi < 2; ++mi)
#pragma unroll
        for (int ni = 0; ni < 4; ++ni)
#pragma unroll
          for (int q = 0; q < 4; ++q) {
            float e = s[mi][ni][q] * 0.125f;
            if (dm && (kt * 64 + ni * 16 + ro) > (qrow0 + mi * 16 + hi * 4 + q)) e = -1e9f;
            s[mi][ni][q] = e;
          }

      float fac[2][4];
#pragma unroll
      for (int mi = 0; mi < 2; ++mi)
#pragma unroll
        for (int q = 0; q < 4; ++q) {
          float rm = s[mi][0][q];
#pragma unroll
          for (int ni = 1; ni < 4; ++ni) rm = fmaxf(rm, s[mi][ni][q]);
          rm = wred_max16(rm);
          const float mn = fmaxf(mrun[mi][q], rm);
          fac[mi][q] = __expf(mrun[mi][q] - mn);
          mrun[mi][q] = mn;
        }
#pragma unroll
      for (int mi = 0; mi < 2; ++mi)
#pragma unroll
        for (int q = 0; q < 4; ++q) {
          float rs = 0.f;
#pragma unroll
          for (int ni = 0; ni < 4; ++ni) {
            const float pv = __expf(s[mi][ni][q] - mrun[mi][q]);
            s[mi][ni][q] = pv;
            rs += pv;
          }
          rs = wred_sum16(rs);
          lrun[mi][q] = lrun[mi][q] * fac[mi][q] + rs;
        }
#pragma unroll
      for (int mi = 0; mi < 2; ++mi)
#pragma unroll
        for (int di = 0; di < 4; ++di)
#pragma unroll
          for (int q = 0; q < 4; ++q) o[mi][di][q] *= fac[mi][q];

#pragma unroll
      for (int mi = 0; mi < 2; ++mi)
#pragma unroll
        for (int ni = 0; ni < 4; ++ni)
#pragma unroll
          for (int q = 0; q < 4; ++q) {
            const int row = mi * 16 + hi * 4 + q;
            const int col = ni * 16 + ro;
            const int sc  = ((col >> 3) ^ (row & 7)) * 8 + (col & 7);
            Pl[w][row * 64 + sc] = f2b(s[mi][ni][q]);
          }

      bf16x8 pa[2][2];
#pragma unroll
      for (int mi = 0; mi < 2; ++mi)
#pragma unroll
        for (int ks = 0; ks < 2; ++ks) {
          const int row = mi * 16 + ro;
          pa[mi][ks] = *(const bf16x8*)&Pl[w][row * 64 + (((ks << 2) + hi) ^ (row & 7)) * 8];
        }

#pragma unroll
      for (int di = 0; di < 4; ++di)
#pragma unroll
        for (int ks = 0; ks < 2; ++ks) {
          const int r = di * 16 + ro;
          const bf16x8 vf = *(const bf16x8*)&Vs[cur][r * 64 + (((ks << 2) + hi) ^ (r & 7)) * 8];
#pragma unroll
          for (int mi = 0; mi < 2; ++mi)
            o[mi][di] = __builtin_amdgcn_mfma_f32_16x16x32_bf16(pa[mi][ks], vf, o[mi][di], 0, 0, 0);
        }
    }
    cur ^= 1;
  }

#pragma unroll
  for (int mi = 0; mi < 2; ++mi)
#pragma unroll
    for (int di = 0; di < 4; ++di)
#pragma unroll
      for (int q = 0; q < 4; ++q) {
        const float val = o[mi][di][q] / lrun[mi][q];
        Og[obase + (size_t)(qrow0 + mi * 16 + hi * 4 + q) * 1024 + di * 16 + ro] = f2b(val);
      }
}

// ---------------- host orchestration ----------------

extern "C" void kernel_launch(void* const* d_in, const int* in_sizes, int n_in,
                              void* d_out, int out_size, void* d_ws, size_t ws_size,
                              hipStream_t stream) {
  (void)in_sizes; (void)n_in; (void)out_size; (void)ws_size;
  const int*   dec = (const int*)d_in[0];
  const float* enc = (const float*)d_in[2];
  const float* emb = (const float*)d_in[4];
  const float* pe  = (const float*)d_in[5];
  const float* wq  = (const float*)d_in[6];
  const float* bq  = (const float*)d_in[7];
  const float* wk  = (const float*)d_in[8];
  const float* bk  = (const float*)d_in[9];
  const float* wv  = (const float*)d_in[10];
  const float* bv  = (const float*)d_in[11];
  const float* wo  = (const float*)d_in[12];
  const float* bo  = (const float*)d_in[13];
  const float* w1  = (const float*)d_in[14];
  const float* b1  = (const float*)d_in[15];
  const float* w2  = (const float*)d_in[16];
  const float* b2  = (const float*)d_in[17];
  const float* lng = (const float*)d_in[18];
  const float* lnb = (const float*)d_in[19];

  const size_t SZ_ACT = 4194304ull;     // 4096*1024

  char* p = (char*)d_ws;
  auto alloc = [&](size_t bytes) { char* r = p; p += (bytes + 255) & ~(size_t)255; return r; };
  unsigned short* qkvw  = (unsigned short*)alloc(3ull * 3 * 1048576 * 2);  // [L][3072][1024]
  unsigned short* kvw   = (unsigned short*)alloc(3ull * 2 * 1048576 * 2);  // [6144][1024]
  unsigned short* wqxb  = (unsigned short*)alloc(3ull * 1048576 * 2);      // [L][1024][1024]
  unsigned short* Wob   = (unsigned short*)alloc(6291456ull * 2);          // [L][2][1024][1024]
  unsigned short* W1b   = (unsigned short*)alloc(12582912ull * 2);
  unsigned short* W2b   = (unsigned short*)alloc(12582912ull * 2);
  unsigned short* encb  = (unsigned short*)alloc(SZ_ACT * 2);
  float*          x     = (float*)alloc(SZ_ACT * 4);
  float*          c     = (float*)alloc(SZ_ACT * 4);
  unsigned short* hb    = (unsigned short*)alloc(SZ_ACT * 2);
  unsigned short* qkvb  = (unsigned short*)alloc(4096ull * 3072 * 2);
  unsigned short* kvb   = (unsigned short*)alloc(4096ull * 6144 * 2);      // merged 3-layer K/V
  unsigned short* qb    = (unsigned short*)alloc(SZ_ACT * 2);
  unsigned short* vtbS  = (unsigned short*)alloc(SZ_ACT * 2);              // self V^T [B][H][64][512]
  unsigned short* vtb3  = (unsigned short*)alloc(3ull * SZ_ACT * 2);       // cross V^T per layer
  unsigned short* mid   = (unsigned short*)alloc(4096ull * 4096 * 2);
  float*          pbuf  = (float*)alloc(4ull * SZ_ACT * 4);                // split-K partials
  float*          qkvbias = (float*)alloc(3ull * 3072 * 4);
  float*          kvbias  = (float*)alloc(3ull * 2048 * 4);

  cvt_kernel<<<2048, 256, 0, stream>>>(wo, Wob, 1572864);
  cvt_kernel<<<2048, 256, 0, stream>>>(w1, W1b, 3145728);
  cvt_kernel<<<2048, 256, 0, stream>>>(w2, W2b, 3145728);
  cvt_kernel<<<2048, 256, 0, stream>>>(enc, encb, 1048576);
  pack_w<<<dim3(1024, 3, 3), 256, 0, stream>>>(wq, wk, wv, 0, qkvw, 3);
  pack_w<<<dim3(1024, 2, 3), 256, 0, stream>>>(wk, wv, wv, 1, kvw, 2);
  pack_w<<<dim3(1024, 1, 3), 256, 0, stream>>>(wq, wq, wq, 1, wqxb, 1);
  pack_bias<<<dim3(3, 3), 256, 0, stream>>>(bq, bk, bv, 0, qkvbias, 3);
  pack_bias<<<dim3(2, 3), 256, 0, stream>>>(bk, bv, bv, 1, kvbias, 2);
  embed_kernel<<<4096, 256, 0, stream>>>(dec, emb, pe, x);

  // merged cross-attn K/V for all 3 layers; V written transposed to vtb3[l]
  gemm8p<0, 2><<<16 * 24, 512, 0, stream>>>(encb, kvw, kvbias, 6144, kvb, vtb3);

  const dim3 gAttn(4, 16, 8);

  for (int l = 0; l < 3; ++l) {
    const float* g0 = lng + (l * 3 + 0) * 1024; const float* e0 = lnb + (l * 3 + 0) * 1024;
    const float* g1 = lng + (l * 3 + 1) * 1024; const float* e1 = lnb + (l * 3 + 1) * 1024;
    const float* g2 = lng + (l * 3 + 2) * 1024; const float* e2 = lnb + (l * 3 + 2) * 1024;

    // ---- self-attention sublayer ----
    if (l == 0)
      ln_kernel<<<4096, 64, 0, stream>>>(x, g0, e0, hb);
    // (for l=1,2 hb was produced by reduce4_ln of the previous layer)
    gemm8p<0, 1><<<16 * 12, 512, 0, stream>>>(hb, qkvw + (size_t)l * 3 * 1048576,
        qkvbias + l * 3072, 3072, qkvb, vtbS);
    attn_kernel<true><<<gAttn, 256, 0, stream>>>(qkvb, 3072, qkvb + 1024, 3072, vtbS, hb);
    gemm_bt<EPI_RES, 128, 64><<<32 * 16, 256, 0, stream>>>(hb, Wob + (size_t)(l * 2) * 1048576,
        bo + (l * 2) * 1024, 1024, 1024, 16, x, x, nullptr);

    // ---- cross-attention sublayer ----
    ln_kernel<<<4096, 64, 0, stream>>>(x, g1, e1, hb);
    gemm_bt<EPI_BF16, 128, 64><<<32 * 16, 256, 0, stream>>>(hb, wqxb + (size_t)l * 1048576,
        bq + (l * 2 + 1) * 1024, 1024, 1024, 16, qb, nullptr, nullptr);
    attn_kernel<false><<<gAttn, 256, 0, stream>>>(qb, 1024, kvb + l * 2048, 6144,
        vtb3 + (size_t)l * SZ_ACT, hb);
    gemm_bt<EPI_RES2, 128, 64><<<32 * 16, 256, 0, stream>>>(hb, Wob + (size_t)(l * 2 + 1) * 1048576,
        bo + (l * 2 + 1) * 1024, 1024, 1024, 16, c, x, x);

    // ---- FFN sublayer (residual is c, per reference quirk) ----
    ln_kernel<<<4096, 64, 0, stream>>>(x, g2, e2, hb);
    gemm8p<1, 0><<<16 * 16, 512, 0, stream>>>(hb, W1b + (size_t)l * 4194304,
        b1 + l * 4096, 4096, mid, nullptr);
    gemm_sk8<<<256, 512, 0, stream>>>(mid, W2b + (size_t)l * 4194304, pbuf);
    if (l == 2) {
      reduce4_kernel<<<2048, 256, 0, stream>>>(c, pbuf, b2 + l * 1024, (float*)d_out);
    } else {
      // fused: x = c + sum(p) + b2;  hb = LN(x) with NEXT layer's norm1 params
      const float* gn = lng + ((l + 1) * 3 + 0) * 1024;
      const float* en = lnb + ((l + 1) * 3 + 0) * 1024;
      reduce4_ln_kernel<<<4096, 64, 0, stream>>>(c, pbuf, b2 + l * 1024, gn, en, x, hb);
    }
  }
}